// Round 1
// baseline (180.152 us; speedup 1.0000x reference)
//
#include <hip/hip_runtime.h>
#include <float.h>
#include <math.h>

#define NBATCH   4096
#define NAGENT   16
#define NTASK    16
#define DDIM     128
#define G        8      // batches per block
#define NTHREADS 256

__global__ __launch_bounds__(NTHREADS, 2)
void alloc_policy_kernel(const float* __restrict__ task_embeds,
                         const float* __restrict__ task_nonag,
                         const float* __restrict__ agent_embeds,
                         const unsigned char* __restrict__ task_mask,
                         const float* __restrict__ agent_mask,
                         const float* __restrict__ gumbels,
                         const float* __restrict__ W_count,
                         const float* __restrict__ b_count,
                         const float* __restrict__ W_upd,
                         const float* __restrict__ b_upd,
                         float* __restrict__ out)
{
    // LDS budget: 64K + 8K + 4K + ~1.3K ~= 77.5 KB -> 2 blocks/CU
    __shared__ __align__(16) float te[G][NTASK][DDIM];     // evolving task embeds
    __shared__ __align__(16) float scratch[G][2 * DDIM];   // relu-input row, then matvec partials
    __shared__ __align__(16) float ag_l[G][DDIM];          // current agent embed
    __shared__ float counts_l[G][NTASK];
    __shared__ float nonag_l[G][NTASK];
    __shared__ unsigned char mask_l[G * NTASK];
    __shared__ int   tstar_s[G];
    __shared__ float hsel_s[G];
    __shared__ float agm_s[G];

    const int tid = threadIdx.x;
    const int b0  = blockIdx.x * G;

    // logits-phase mapping: 8 groups x 32 lanes, 4 d-channels per lane
    const int lg = tid >> 5;
    const int lc = tid & 31;
    const int d0 = lc * 4;

    // matvec-phase mapping: 128 columns x 2 i-halves
    const int mj = tid & 127;
    const int mh = tid >> 7;

    const float scalef = sqrtf((float)DDIM);

    // per-thread constants
    const float4 w0r = *(const float4*)(W_count + d0);          // W_count[0][d0..d0+3]
    const float4 w1r = *(const float4*)(W_count + DDIM + d0);   // W_count[1][...]
    const float4 bcr = *(const float4*)(b_count + d0);
    const float  bu  = b_upd[mj];

    // ---- init: te <- task_embeds[b0..b0+G), counts<-0, nonag, mask
    {
        const float4* src = (const float4*)(task_embeds + (size_t)b0 * NTASK * DDIM);
        float4* dst = (float4*)(&te[0][0][0]);
        #pragma unroll
        for (int k = 0; k < (G * NTASK * DDIM / 4) / NTHREADS; ++k)  // 16
            dst[k * NTHREADS + tid] = src[k * NTHREADS + tid];
        if (tid < G * NTASK) {
            (&nonag_l[0][0])[tid]  = task_nonag[b0 * NTASK + tid];
            (&counts_l[0][0])[tid] = 0.0f;
            mask_l[tid] = task_mask[b0 * NTASK + tid];
        }
    }
    __syncthreads();

    for (int a = 0; a < NAGENT; ++a) {
        // ---- load agent embed (kept in reg for logits, LDS copy for matvec staging)
        const float4 ag4 = *(const float4*)(agent_embeds +
                              ((size_t)(b0 + lg) * NAGENT + a) * DDIM + d0);
        *(float4*)(&ag_l[lg][d0]) = ag4;

        // ---- logits[t] = dot(ag, te[t] + cnt_e[t]) over 128 d, 32-lane reduce
        float keep = 0.0f;
        #pragma unroll
        for (int t = 0; t < NTASK; ++t) {
            const float nn = nonag_l[lg][t];
            const float cc = counts_l[lg][t];
            const float4 te4 = *(const float4*)(&te[lg][t][d0]);
            float acc;
            float c0 = fmaf(cc, w1r.x, fmaf(nn, w0r.x, bcr.x));
            acc = ag4.x * (te4.x + c0);
            c0 = fmaf(cc, w1r.y, fmaf(nn, w0r.y, bcr.y));
            acc = fmaf(ag4.y, te4.y + c0, acc);
            c0 = fmaf(cc, w1r.z, fmaf(nn, w0r.z, bcr.z));
            acc = fmaf(ag4.z, te4.z + c0, acc);
            c0 = fmaf(cc, w1r.w, fmaf(nn, w0r.w, bcr.w));
            acc = fmaf(ag4.w, te4.w + c0, acc);
            acc += __shfl_xor(acc, 16);
            acc += __shfl_xor(acc, 8);
            acc += __shfl_xor(acc, 4);
            acc += __shfl_xor(acc, 2);
            acc += __shfl_xor(acc, 1);
            if (lc == t) keep = acc;
        }

        // ---- softmax + argmax + output + counts (16 lanes per batch group)
        if (lc < NTASK) {
            const int t  = lc;
            const int gb = b0 + lg;
            float z = keep / scalef;
            if (mask_l[lg * NTASK + t]) z = -FLT_MAX;
            z = z + gumbels[((size_t)a * NBATCH + gb) * NTASK + t];

            float m = z;
            m = fmaxf(m, __shfl_xor(m, 8));
            m = fmaxf(m, __shfl_xor(m, 4));
            m = fmaxf(m, __shfl_xor(m, 2));
            m = fmaxf(m, __shfl_xor(m, 1));
            const float e = expf(z - m);
            float ssum = e;
            ssum += __shfl_xor(ssum, 8);
            ssum += __shfl_xor(ssum, 4);
            ssum += __shfl_xor(ssum, 2);
            ssum += __shfl_xor(ssum, 1);
            const float sft = e / ssum;

            // argmax over soft with first-index tie-break (matches jnp.argmax)
            float bv = sft; int bi = t;
            #pragma unroll
            for (int k = 8; k >= 1; k >>= 1) {
                const float ov = __shfl_xor(bv, k);
                const int   oi = __shfl_xor(bi, k);
                if (ov > bv || (ov == bv && oi < bi)) { bv = ov; bi = oi; }
            }

            const float agm = 1.0f - agent_mask[(size_t)gb * NAGENT + a];
            const float onehot = (t == bi) ? 1.0f : 0.0f;
            const float hh = ((onehot - sft) + sft) * agm;  // exact 0 for t != t*

            out[((size_t)gb * NAGENT + a) * NTASK + t] = hh;
            counts_l[lg][t] = counts_l[lg][t] + hh * 0.1f;

            if (t == 0)  tstar_s[lg] = bi;
            if (t == bi) { hsel_s[lg] = hh; agm_s[lg] = agm; }
        }
        __syncthreads();

        // ---- stage relu(concat(te[t*], ag)) into scratch[g][0..255]
        {
            const int ts = tstar_s[lg];
            const int i0 = lc * 8;
            #pragma unroll
            for (int kk = 0; kk < 2; ++kk) {
                const int i = i0 + kk * 4;
                float4 v = (i < DDIM) ? *(const float4*)(&te[lg][ts][i])
                                      : *(const float4*)(&ag_l[lg][i - DDIM]);
                v.x = fmaxf(v.x, 0.0f);
                v.y = fmaxf(v.y, 0.0f);
                v.z = fmaxf(v.z, 0.0f);
                v.w = fmaxf(v.w, 0.0f);
                *(float4*)(&scratch[lg][i]) = v;
            }
        }
        __syncthreads();

        // ---- matvec: upd[j] = b_upd[j] + sum_i relu_in[i] * W_upd[i][j]
        float acc[G];
        #pragma unroll
        for (int g = 0; g < G; ++g) acc[g] = 0.0f;
        const int ibase = mh * DDIM;
        #pragma unroll 4
        for (int ii = 0; ii < DDIM; ii += 4) {
            const int i = ibase + ii;
            const float w0 = W_upd[(i + 0) * DDIM + mj];
            const float w1 = W_upd[(i + 1) * DDIM + mj];
            const float w2 = W_upd[(i + 2) * DDIM + mj];
            const float w3 = W_upd[(i + 3) * DDIM + mj];
            #pragma unroll
            for (int g = 0; g < G; ++g) {
                const float4 in4 = *(const float4*)(&scratch[g][i]);  // broadcast read
                acc[g] = fmaf(in4.x, w0, acc[g]);
                acc[g] = fmaf(in4.y, w1, acc[g]);
                acc[g] = fmaf(in4.z, w2, acc[g]);
                acc[g] = fmaf(in4.w, w3, acc[g]);
            }
        }
        __syncthreads();   // all scratch reads done before reuse as partial buffer
        if (mh == 1) {
            #pragma unroll
            for (int g = 0; g < G; ++g) scratch[g][mj] = acc[g];
        }
        __syncthreads();
        if (mh == 0) {
            #pragma unroll
            for (int g = 0; g < G; ++g) {
                const float u = (acc[g] + scratch[g][mj]) + bu;
                te[g][tstar_s[g]][mj] += (u * hsel_s[g]) * agm_s[g];
            }
        }
        __syncthreads();
    }
}

extern "C" void kernel_launch(void* const* d_in, const int* in_sizes, int n_in,
                              void* d_out, int out_size, void* d_ws, size_t ws_size,
                              hipStream_t stream) {
    const float*         task_embeds  = (const float*)d_in[0];
    const float*         task_nonag   = (const float*)d_in[1];
    const float*         agent_embeds = (const float*)d_in[2];
    const unsigned char* task_mask    = (const unsigned char*)d_in[3];
    const float*         agent_mask   = (const float*)d_in[4];
    const float*         gumbels      = (const float*)d_in[5];
    const float*         W_count      = (const float*)d_in[6];
    const float*         b_count      = (const float*)d_in[7];
    const float*         W_upd        = (const float*)d_in[8];
    const float*         b_upd        = (const float*)d_in[9];
    float* out = (float*)d_out;

    dim3 grid(NBATCH / G);
    dim3 block(NTHREADS);
    hipLaunchKernelGGL(alloc_policy_kernel, grid, block, 0, stream,
                       task_embeds, task_nonag, agent_embeds, task_mask,
                       agent_mask, gumbels, W_count, b_count, W_upd, b_upd, out);
}